// Round 9
// baseline (67.144 us; speedup 1.0000x reference)
//
#include <hip/hip_runtime.h>
#include <hip/hip_bf16.h>

#define Hd 64
#define Sd 128
#define Bd 64
#define Nn 8192
#define EPSd 1e-5f

__device__ __forceinline__ float wred_sum(float v) {
    for (int m = 32; m; m >>= 1) v += __shfl_xor(v, m);
    return v;
}
__device__ __forceinline__ float wred_max(float v) {
    for (int m = 32; m; m >>= 1) v = fmaxf(v, __shfl_xor(v, m));
    return v;
}
// 64-lane inclusive scan
__device__ __forceinline__ float wscan_incl(float x, int lane) {
    #pragma unroll
    for (int d = 1; d < 64; d <<= 1) {
        float t = __shfl_up(x, d);
        if (lane >= d) x += t;
    }
    return x;
}

// A: conv1+bn1+relu -> conv2+bn2+relu -> (LDS) -> Wh, s1, s2  (32 nodes/block, 256 blocks)
__global__ __launch_bounds__(256) void kA_feat_wh(
        const float* __restrict__ x,
        const float* __restrict__ c1w, const float* __restrict__ c1b,
        const float* __restrict__ b1g, const float* __restrict__ b1b,
        const float* __restrict__ b1m, const float* __restrict__ b1v,
        const float* __restrict__ c2w, const float* __restrict__ c2b,
        const float* __restrict__ b2g, const float* __restrict__ b2b,
        const float* __restrict__ b2m, const float* __restrict__ b2v,
        const float* __restrict__ gW, const float* __restrict__ gWb,
        const float* __restrict__ a1, const float* __restrict__ a2,
        float* __restrict__ Wh, float* __restrict__ s1, float* __restrict__ s2) {
    __shared__ float buf[14464];           // phase1: h1[0..2176) | wtk[2176..14464)
    float* h1  = buf;                      // [col][cin], 34*64
    float* wtk = buf + 2176;               // [(k*16+cin4)*256 + c*4 + j]
    int b  = blockIdx.x >> 2;
    int s0 = (blockIdx.x & 3) * 32;
    int tid = threadIdx.x;
    // coalesced read of c2w, scattered LDS write
    for (int idx = tid; idx < 12288; idx += 256) {
        int c   = idx / 192;
        int rem = idx - c * 192;
        int cin = rem / 3;
        int k   = rem - cin * 3;
        int cin4 = cin >> 2, j = cin & 3;
        wtk[(k * 16 + cin4) * 256 + c * 4 + j] = c2w[idx];
    }
    for (int idx = tid; idx < 34 * 64; idx += 256) {
        int cin = idx & 63;
        int col = idx >> 6;
        int s   = s0 - 1 + col;
        float v = 0.f;
        if (s >= 0 && s < Sd) {
            float xm = (s > 0)      ? x[b * Sd + s - 1] : 0.f;
            float x0 = x[b * Sd + s];
            float xp = (s < Sd - 1) ? x[b * Sd + s + 1] : 0.f;
            float y  = c1w[cin * 3 + 0] * xm + c1w[cin * 3 + 1] * x0 + c1w[cin * 3 + 2] * xp + c1b[cin];
            float inv = b1g[cin] * rsqrtf(b1v[cin] + EPSd);
            v = fmaxf(y * inv + (b1b[cin] - b1m[cin] * inv), 0.f);
        }
        h1[col * 64 + cin] = v;
    }
    __syncthreads();
    int c = tid & 63, g = tid >> 6;
    float inv2 = b2g[c] * rsqrtf(b2v[c] + EPSd);
    float sh2  = b2b[c] - b2m[c] * inv2;
    float acc[8];
    #pragma unroll
    for (int p = 0; p < 8; ++p) acc[p] = c2b[c];
    {
        const float4* h14 = (const float4*)h1;
        const float4* wt4 = (const float4*)wtk;
        for (int cin4 = 0; cin4 < 16; ++cin4) {
            float4 xs[10];
            #pragma unroll
            for (int q = 0; q < 10; ++q) xs[q] = h14[(g * 8 + q) * 16 + cin4];
            #pragma unroll
            for (int k = 0; k < 3; ++k) {
                float4 w4 = wt4[(k * 16 + cin4) * 64 + c];
                #pragma unroll
                for (int p = 0; p < 8; ++p) {
                    float4 x4 = xs[p + k];
                    acc[p] += w4.x * x4.x + w4.y * x4.y + w4.z * x4.z + w4.w * x4.w;
                }
            }
        }
    }
    __syncthreads();   // conv reads done; safe to overwrite
    float*  xfl  = buf;                    // [sl][c], 32*64
    float4* gWT4 = (float4*)(buf + 2176);  // [kk4*64 + h]
    #pragma unroll
    for (int p = 0; p < 8; ++p)
        xfl[(g * 8 + p) * 64 + c] = fmaxf(acc[p] * inv2 + sh2, 0.f);
    for (int fidx = tid; fidx < 1024; fidx += 256) {
        int h_ = fidx >> 4, kk4 = fidx & 15;
        gWT4[kk4 * 64 + h_] = ((const float4*)gW)[fidx];
    }
    __syncthreads();
    int h = tid & 63, w = tid >> 6;
    float4 wreg[16];
    #pragma unroll
    for (int kk4 = 0; kk4 < 16; ++kk4) wreg[kk4] = gWT4[kk4 * 64 + h];
    float va1 = a1[h], va2 = a2[h], bias = gWb[h];
    const float4* xf4 = (const float4*)xfl;
    int n0 = b * Sd + s0;
    for (int q = 0; q < 8; ++q) {
        int sl = w * 8 + q;
        float accw = bias;
        #pragma unroll
        for (int kk4 = 0; kk4 < 16; ++kk4) {
            float4 x4 = xf4[sl * 16 + kk4];
            accw += wreg[kk4].x * x4.x + wreg[kk4].y * x4.y + wreg[kk4].z * x4.z + wreg[kk4].w * x4.w;
        }
        int n = n0 + sl;
        Wh[n * 64 + h] = accw;
        float r1 = wred_sum(accw * va1);
        float r2 = wred_sum(accw * va2);
        if (h == 0) { s1[n] = r1; s2[n] = r2; }
    }
}

// B: partial ranks AND partial k-counts (32 parts of 256 keys) + per-part max
__global__ __launch_bounds__(256) void kB_rank(
        const float* __restrict__ s2, const float* __restrict__ s1,
        const float* __restrict__ gab,
        int* __restrict__ rankPart, int* __restrict__ kPart,
        float* __restrict__ pmax) {
    __shared__ float4 ts4[64];
    int bid = blockIdx.x;
    int jg = bid >> 5, part = bid & 31;
    int tid = threadIdx.x;
    if (tid < 64) ts4[tid] = ((const float4*)(s2 + part * 256))[tid];
    __syncthreads();
    if (jg == 0 && tid < 64) {
        float4 t4 = ts4[tid];
        float m = fmaxf(fmaxf(t4.x, t4.y), fmaxf(t4.z, t4.w));
        m = wred_max(m);
        if (tid == 0) pmax[part] = m;
    }
    int j = jg * 256 + tid;
    float tj = s2[j];
    float negc = -(s1[j] + gab[0]);
    int jloc = j - part * 256;
    int cntR = 0, cntK = 0;
    #pragma unroll 4
    for (int q = 0; q < 64; ++q) {
        float4 t4 = ts4[q];
        int rb = q * 4;
        cntR += (t4.x < tj || (t4.x == tj && rb     < jloc)) ? 1 : 0;
        cntR += (t4.y < tj || (t4.y == tj && rb + 1 < jloc)) ? 1 : 0;
        cntR += (t4.z < tj || (t4.z == tj && rb + 2 < jloc)) ? 1 : 0;
        cntR += (t4.w < tj || (t4.w == tj && rb + 3 < jloc)) ? 1 : 0;
        cntK += (t4.x <= negc) ? 1 : 0;
        cntK += (t4.y <= negc) ? 1 : 0;
        cntK += (t4.z <= negc) ? 1 : 0;
        cntK += (t4.w <= negc) ? 1 : 0;
    }
    rankPart[part * 8192 + j] = cntR;
    kPart[part * 8192 + j]    = cntK;
}

// C: sum partials -> jsorted (index scatter), e^t / e^{0.2t} in sorted order, kk
__global__ __launch_bounds__(256) void kC_scatter(
        const float* __restrict__ s2,
        const int* __restrict__ rankPart, const int* __restrict__ kPart,
        int* __restrict__ jsorted, float* __restrict__ e1so, float* __restrict__ e2so,
        int* __restrict__ kk) {
    int j = blockIdx.x * 256 + threadIdx.x;
    int r = 0, kq = 0;
    #pragma unroll
    for (int p = 0; p < 32; ++p) { r += rankPart[p * 8192 + j]; kq += kPart[p * 8192 + j]; }
    float t = s2[j];
    jsorted[r] = j;
    e1so[r] = expf(t);
    e2so[r] = expf(0.2f * t);
    kk[j] = kq;
}

// D: dual-role, 128 blocks. bid<64: chunk sums. bid>=64: chunk-local prefixes (no base).
__global__ __launch_bounds__(256) void kD_dual(
        const float* __restrict__ Wh, const int* __restrict__ jsorted,
        const float* __restrict__ e1so, const float* __restrict__ e2so,
        float* __restrict__ csP, float* __restrict__ csN,
        float* __restrict__ csp, float* __restrict__ csn,
        float* __restrict__ PLpos, float* __restrict__ PLneg,
        float* __restrict__ pLp, float* __restrict__ pLn) {
    __shared__ float ldsA[4][64], ldsB[4][64];
    int bid = blockIdx.x, tid = threadIdx.x;
    int h = tid & 63, w = tid >> 6;
    if (bid < 64) {
        int ch = bid;
        int rb = ch * 128 + w * 32;
        double aP = 0.0, aN = 0.0;
        #pragma unroll
        for (int r = 0; r < 32; ++r) {
            int j = jsorted[rb + r];
            float wv = Wh[j * 64 + h];
            aP += e1so[rb + r] * wv;
            aN += e2so[rb + r] * wv;
        }
        ldsA[w][h] = (float)aP; ldsB[w][h] = (float)aN;
        __syncthreads();
        if (w == 0) {
            csP[ch * 64 + h] = ldsA[0][h] + ldsA[1][h] + ldsA[2][h] + ldsA[3][h];
        } else if (w == 1) {
            csN[ch * 64 + h] = ldsB[0][h] + ldsB[1][h] + ldsB[2][h] + ldsB[3][h];
        } else if (w == 2) {
            float vv = e1so[ch * 128 + h] + e1so[ch * 128 + 64 + h];
            vv = wred_sum(vv);
            if (h == 0) csp[ch] = vv;
        } else {
            float vv = e2so[ch * 128 + h] + e2so[ch * 128 + 64 + h];
            vv = wred_sum(vv);
            if (h == 0) csn[ch] = vv;
        }
    } else {
        int ch = bid - 64;
        int rb = ch * 128 + w * 32;
        float v[32], u[32];
        #pragma unroll
        for (int r = 0; r < 32; ++r) {
            int j = jsorted[rb + r];
            float wv = Wh[j * 64 + h];
            v[r] = e1so[rb + r] * wv;
            u[r] = e2so[rb + r] * wv;
        }
        double sP = 0.0, sN = 0.0;
        #pragma unroll
        for (int r = 0; r < 32; ++r) { sP += v[r]; sN += u[r]; }
        ldsA[w][h] = (float)sP; ldsB[w][h] = (float)sN;
        __syncthreads();
        float offP = 0.f, offN = 0.f;
        #pragma unroll
        for (int w2 = 0; w2 < 4; ++w2) if (w2 < w) { offP += ldsA[w2][h]; offN += ldsB[w2][h]; }
        double a = 0.0;
        #pragma unroll
        for (int r = 0; r < 32; ++r) { PLpos[(rb + r) * 64 + h] = offP + (float)a; a += v[r]; }
        a = 0.0;
        #pragma unroll
        for (int r = 0; r < 32; ++r) { PLneg[(rb + r) * 64 + h] = offN + (float)a; a += u[r]; }
        if (w == 0) {
            int lane = h;
            float v0 = e1so[ch * 128 + lane], v1 = e1so[ch * 128 + 64 + lane];
            float i0 = wscan_incl(v0, lane);
            float t0 = __shfl(i0, 63);
            float i1 = wscan_incl(v1, lane);
            pLp[ch * 128 + lane]      = i0 - v0;
            pLp[ch * 128 + 64 + lane] = t0 + i1 - v1;
        } else if (w == 1) {
            int lane = h;
            float v0 = e2so[ch * 128 + lane], v1 = e2so[ch * 128 + 64 + lane];
            float i0 = wscan_incl(v0, lane);
            float t0 = __shfl(i0, 63);
            float i1 = wscan_incl(v1, lane);
            pLn[ch * 128 + lane]      = i0 - v0;
            pLn[ch * 128 + 64 + lane] = t0 + i1 - v1;
        }
    }
}

// F: per-node hp + time-attn; per-block partial pool (no h2). 512 blocks x 256.
// cpP/cpN built with wave-wide scans (lane=chunk), LDS stride 65 to kill bank conflicts.
__global__ __launch_bounds__(256) void kF_node(
        const float* __restrict__ s1, const int* __restrict__ kk,
        const float* __restrict__ pmax, const float* __restrict__ gab,
        const float* __restrict__ PLpos, const float* __restrict__ PLneg,
        const float* __restrict__ pLp, const float* __restrict__ pLn,
        const float* __restrict__ csP, const float* __restrict__ csN,
        const float* __restrict__ csp, const float* __restrict__ csn,
        const float* __restrict__ taW, const float* __restrict__ tab,
        float* __restrict__ pp) {
    __shared__ float4 wt4[1024];               // taW: [kk4*64 + h]
    __shared__ float cpP[65 * 65], cpN[65 * 65]; // [ch][h] stride 65 (pad)
    __shared__ float cpps[65], cpns[65];
    __shared__ float hl[4][64];
    __shared__ float pacc[4][64];
    int tid = threadIdx.x, bid = blockIdx.x;
    int h = tid & 63, w = tid >> 6;
    int lane = h;
    for (int fidx = tid; fidx < 1024; fidx += 256) {
        int h_ = fidx >> 4, kk4 = fidx & 15;
        wt4[kk4 * 64 + h_] = ((const float4*)taW)[fidx];
    }
    // 128 wave-wide scans: lane = ch; wave w handles h = w*16+rep for both mats
    #pragma unroll
    for (int rep = 0; rep < 16; ++rep) {
        int hh = w * 16 + rep;
        float v = csP[lane * 64 + hh];
        float i = wscan_incl(v, lane);
        cpP[lane * 65 + hh] = i - v;
        if (lane == 63) cpP[64 * 65 + hh] = i;
        float v2 = csN[lane * 64 + hh];
        float i2 = wscan_incl(v2, lane);
        cpN[lane * 65 + hh] = i2 - v2;
        if (lane == 63) cpN[64 * 65 + hh] = i2;
    }
    if (w == 2) {
        float v = csp[lane];
        float i = wscan_incl(v, lane);
        cpps[lane] = i - v;
        if (lane == 63) cpps[64] = i;
    } else if (w == 3) {
        float v = csn[lane];
        float i = wscan_incl(v, lane);
        cpns[lane] = i - v;
        if (lane == 63) cpns[64] = i;
    }
    float tmx = pmax[tid & 31];
    tmx = wred_max(tmx);
    __syncthreads();
    float gabv = gab[0];
    float tabv = tab[h];
    float Tp  = cpP[64 * 65 + h];
    float ppT = cpps[64];
    float apool = 0.f;
    for (int r = 0; r < 4; ++r) {
        int n = bid * 16 + w * 4 + r;
        float c = s1[n] + gabv;
        int k = kk[n];
        int ch = k >> 7;
        float PLpv = 0.f, PLnv = 0.f, pLpv = 0.f, pLnv = 0.f;
        if (k < Nn) {
            PLpv = PLpos[k * 64 + h]; PLnv = PLneg[k * 64 + h];
            pLpv = pLp[k];            pLnv = pLn[k];
        }
        float Pp = cpP[ch * 65 + h] + PLpv;
        float Pn = cpN[ch * 65 + h] + PLnv;
        float qp = cpps[ch] + pLpv;
        float qn = cpns[ch] + pLnv;
        float z = c + tmx;
        float m = (z >= 0.f) ? z : 0.2f * z;
        float E1 = expf(c - m), E2 = expf(0.2f * c - m);
        float num = E1 * (Tp - Pp) + E2 * Pn;
        float den = E1 * (ppT - qp) + E2 * qn;
        float hp = num / den;
        hl[w][h] = hp;                 // wave-synchronous LDS (same-wave order safe)
        float vv = tabv;
        const float4* hlr = (const float4*)&hl[w][0];
        #pragma unroll
        for (int kk4 = 0; kk4 < 16; ++kk4) {
            float4 w4 = wt4[kk4 * 64 + h];
            float4 x4 = hlr[kk4];
            vv += w4.x * x4.x + w4.y * x4.y + w4.z * x4.z + w4.w * x4.w;
        }
        float mx = wred_max(vv);
        float e = expf(vv - mx);
        float se = wred_sum(e);
        apool += hp * (e / se);
    }
    pacc[w][h] = apool;
    __syncthreads();
    if (w == 0)
        pp[bid * 64 + h] = pacc[0][h] + pacc[1][h] + pacc[2][h] + pacc[3][h];
}

// G: gather 8 partial pools per batch + MLP head -> out
__global__ __launch_bounds__(256) void kG_pool(
        const float* __restrict__ pp,
        const float* __restrict__ p1W, const float* __restrict__ p1b,
        const float* __restrict__ p2W, const float* __restrict__ p2b,
        float* __restrict__ out) {
    __shared__ float pacc[4][64];
    __shared__ float pl[64];
    __shared__ float p1s[32 * 65];
    int tid = threadIdx.x, b = blockIdx.x;
    int w = tid >> 6, h = tid & 63;
    for (int idx = tid; idx < 2048; idx += 256) {
        int q = idx >> 6, kq = idx & 63;
        p1s[q * 65 + kq] = p1W[idx];
    }
    float a = pp[(b * 8 + w) * 64 + h] + pp[(b * 8 + 4 + w) * 64 + h];
    pacc[w][h] = a;
    __syncthreads();
    if (w == 0) {
        float pooled = (pacc[0][h] + pacc[1][h] + pacc[2][h] + pacc[3][h]) * (1.f / 128.f);
        pl[h] = pooled;
        float val = 0.f;
        if (h < 32) {
            float acc = p1b[h];
            #pragma unroll
            for (int kq = 0; kq < 64; ++kq) acc += p1s[h * 65 + kq] * pl[kq];
            val = p2W[h] * fmaxf(acc, 0.f);
        }
        val = wred_sum(val);
        if (h == 0) out[b] = val + p2b[0];
    }
}

extern "C" void kernel_launch(void* const* d_in, const int* in_sizes, int n_in,
                              void* d_out, int out_size, void* d_ws, size_t ws_size,
                              hipStream_t stream) {
    const float* x    = (const float*)d_in[0];
    const float* c1w  = (const float*)d_in[1];
    const float* c1b  = (const float*)d_in[2];
    const float* b1g  = (const float*)d_in[3];
    const float* b1b  = (const float*)d_in[4];
    const float* b1m  = (const float*)d_in[5];
    const float* b1v  = (const float*)d_in[6];
    const float* c2w  = (const float*)d_in[7];
    const float* c2b  = (const float*)d_in[8];
    const float* b2g  = (const float*)d_in[9];
    const float* b2b  = (const float*)d_in[10];
    const float* b2m  = (const float*)d_in[11];
    const float* b2v  = (const float*)d_in[12];
    const float* gW   = (const float*)d_in[13];
    const float* gWb  = (const float*)d_in[14];
    const float* ga1  = (const float*)d_in[15];
    const float* ga2  = (const float*)d_in[16];
    const float* gab  = (const float*)d_in[17];
    const float* taW  = (const float*)d_in[18];
    const float* tab  = (const float*)d_in[19];
    const float* p1W  = (const float*)d_in[20];
    const float* p1b  = (const float*)d_in[21];
    const float* p2W  = (const float*)d_in[22];
    const float* p2b  = (const float*)d_in[23];
    float* out = (float*)d_out;

    float* ws = (float*)d_ws;
    float* Wh      = ws;                    // 524288
    float* s1      = Wh + 524288;           // 8192
    float* s2v     = s1 + 8192;             // 8192
    float* e1so    = s2v + 8192;            // 8192
    float* e2so    = e1so + 8192;           // 8192
    float* csP     = e2so + 8192;           // 4096
    float* csN     = csP + 4096;            // 4096
    float* csp     = csN + 4096;            // 64
    float* csn     = csp + 64;              // 64
    float* pmax    = csn + 64;              // 64 (32 used)
    float* pLp     = pmax + 64;             // 8192
    float* pLn     = pLp + 8192;            // 8192
    float* ppool   = pLn + 8192;            // 32768 (512*64)
    float* PLpos   = ppool + 32768;         // 524288
    float* PLneg   = PLpos + 524288;        // 524288
    int*   jsorted = (int*)(PLneg + 524288);// 8192
    int*   kk      = jsorted + 8192;        // 8192
    int*   rankPart= kk + 8192;             // 262144
    int*   kPart   = rankPart + 262144;     // 262144

    kA_feat_wh<<<256, 256, 0, stream>>>(x, c1w, c1b, b1g, b1b, b1m, b1v,
                                        c2w, c2b, b2g, b2b, b2m, b2v,
                                        gW, gWb, ga1, ga2, Wh, s1, s2v);
    kB_rank<<<1024, 256, 0, stream>>>(s2v, s1, gab, rankPart, kPart, pmax);
    kC_scatter<<<32, 256, 0, stream>>>(s2v, rankPart, kPart, jsorted, e1so, e2so, kk);
    kD_dual<<<128, 256, 0, stream>>>(Wh, jsorted, e1so, e2so, csP, csN, csp, csn,
                                     PLpos, PLneg, pLp, pLn);
    kF_node<<<512, 256, 0, stream>>>(s1, kk, pmax, gab, PLpos, PLneg, pLp, pLn,
                                     csP, csN, csp, csn, taW, tab, ppool);
    kG_pool<<<64, 256, 0, stream>>>(ppool, p1W, p1b, p2W, p2b, out);
}

// Round 10
// 59.008 us; speedup vs baseline: 1.1379x; 1.1379x over previous
//
#include <hip/hip_runtime.h>
#include <hip/hip_bf16.h>

#define Hd 64
#define Sd 128
#define Bd 64
#define Nn 8192
#define EPSd 1e-5f

__device__ __forceinline__ float wred_sum(float v) {
    for (int m = 32; m; m >>= 1) v += __shfl_xor(v, m);
    return v;
}
__device__ __forceinline__ float wred_max(float v) {
    for (int m = 32; m; m >>= 1) v = fmaxf(v, __shfl_xor(v, m));
    return v;
}
// 64-lane inclusive scan
__device__ __forceinline__ float wscan_incl(float x, int lane) {
    #pragma unroll
    for (int d = 1; d < 64; d <<= 1) {
        float t = __shfl_up(x, d);
        if (lane >= d) x += t;
    }
    return x;
}

// A: conv1+bn1+relu -> conv2+bn2+relu -> (LDS) -> Wh, s1, s2  (32 nodes/block, 256 blocks)
__global__ __launch_bounds__(256) void kA_feat_wh(
        const float* __restrict__ x,
        const float* __restrict__ c1w, const float* __restrict__ c1b,
        const float* __restrict__ b1g, const float* __restrict__ b1b,
        const float* __restrict__ b1m, const float* __restrict__ b1v,
        const float* __restrict__ c2w, const float* __restrict__ c2b,
        const float* __restrict__ b2g, const float* __restrict__ b2b,
        const float* __restrict__ b2m, const float* __restrict__ b2v,
        const float* __restrict__ gW, const float* __restrict__ gWb,
        const float* __restrict__ a1, const float* __restrict__ a2,
        float* __restrict__ Wh, float* __restrict__ s1, float* __restrict__ s2) {
    __shared__ float buf[14464];           // phase1: h1[0..2176) | wtk[2176..14464)
    float* h1  = buf;                      // [col][cin], 34*64
    float* wtk = buf + 2176;               // [(k*16+cin4)*256 + c*4 + j]
    int b  = blockIdx.x >> 2;
    int s0 = (blockIdx.x & 3) * 32;
    int tid = threadIdx.x;
    // coalesced read of c2w, scattered LDS write
    for (int idx = tid; idx < 12288; idx += 256) {
        int c   = idx / 192;
        int rem = idx - c * 192;
        int cin = rem / 3;
        int k   = rem - cin * 3;
        int cin4 = cin >> 2, j = cin & 3;
        wtk[(k * 16 + cin4) * 256 + c * 4 + j] = c2w[idx];
    }
    for (int idx = tid; idx < 34 * 64; idx += 256) {
        int cin = idx & 63;
        int col = idx >> 6;
        int s   = s0 - 1 + col;
        float v = 0.f;
        if (s >= 0 && s < Sd) {
            float xm = (s > 0)      ? x[b * Sd + s - 1] : 0.f;
            float x0 = x[b * Sd + s];
            float xp = (s < Sd - 1) ? x[b * Sd + s + 1] : 0.f;
            float y  = c1w[cin * 3 + 0] * xm + c1w[cin * 3 + 1] * x0 + c1w[cin * 3 + 2] * xp + c1b[cin];
            float inv = b1g[cin] * rsqrtf(b1v[cin] + EPSd);
            v = fmaxf(y * inv + (b1b[cin] - b1m[cin] * inv), 0.f);
        }
        h1[col * 64 + cin] = v;
    }
    __syncthreads();
    int c = tid & 63, g = tid >> 6;
    float inv2 = b2g[c] * rsqrtf(b2v[c] + EPSd);
    float sh2  = b2b[c] - b2m[c] * inv2;
    float acc[8];
    #pragma unroll
    for (int p = 0; p < 8; ++p) acc[p] = c2b[c];
    {
        const float4* h14 = (const float4*)h1;
        const float4* wt4 = (const float4*)wtk;
        for (int cin4 = 0; cin4 < 16; ++cin4) {
            float4 xs[10];
            #pragma unroll
            for (int q = 0; q < 10; ++q) xs[q] = h14[(g * 8 + q) * 16 + cin4];
            #pragma unroll
            for (int k = 0; k < 3; ++k) {
                float4 w4 = wt4[(k * 16 + cin4) * 64 + c];
                #pragma unroll
                for (int p = 0; p < 8; ++p) {
                    float4 x4 = xs[p + k];
                    acc[p] += w4.x * x4.x + w4.y * x4.y + w4.z * x4.z + w4.w * x4.w;
                }
            }
        }
    }
    __syncthreads();   // conv reads done; safe to overwrite
    float*  xfl  = buf;                    // [sl][c], 32*64
    float4* gWT4 = (float4*)(buf + 2176);  // [kk4*64 + h]
    #pragma unroll
    for (int p = 0; p < 8; ++p)
        xfl[(g * 8 + p) * 64 + c] = fmaxf(acc[p] * inv2 + sh2, 0.f);
    for (int fidx = tid; fidx < 1024; fidx += 256) {
        int h_ = fidx >> 4, kk4 = fidx & 15;
        gWT4[kk4 * 64 + h_] = ((const float4*)gW)[fidx];
    }
    __syncthreads();
    int h = tid & 63, w = tid >> 6;
    float4 wreg[16];
    #pragma unroll
    for (int kk4 = 0; kk4 < 16; ++kk4) wreg[kk4] = gWT4[kk4 * 64 + h];
    float va1 = a1[h], va2 = a2[h], bias = gWb[h];
    const float4* xf4 = (const float4*)xfl;
    int n0 = b * Sd + s0;
    for (int q = 0; q < 8; ++q) {
        int sl = w * 8 + q;
        float accw = bias;
        #pragma unroll
        for (int kk4 = 0; kk4 < 16; ++kk4) {
            float4 x4 = xf4[sl * 16 + kk4];
            accw += wreg[kk4].x * x4.x + wreg[kk4].y * x4.y + wreg[kk4].z * x4.z + wreg[kk4].w * x4.w;
        }
        int n = n0 + sl;
        Wh[n * 64 + h] = accw;
        float r1 = wred_sum(accw * va1);
        float r2 = wred_sum(accw * va2);
        if (h == 0) { s1[n] = r1; s2[n] = r2; }
    }
}

// B: partial ranks AND partial k-counts (32 parts of 256 keys) + per-part max
__global__ __launch_bounds__(256) void kB_rank(
        const float* __restrict__ s2, const float* __restrict__ s1,
        const float* __restrict__ gab,
        int* __restrict__ rankPart, int* __restrict__ kPart,
        float* __restrict__ pmax) {
    __shared__ float4 ts4[64];
    int bid = blockIdx.x;
    int jg = bid >> 5, part = bid & 31;
    int tid = threadIdx.x;
    if (tid < 64) ts4[tid] = ((const float4*)(s2 + part * 256))[tid];
    __syncthreads();
    if (jg == 0 && tid < 64) {
        float4 t4 = ts4[tid];
        float m = fmaxf(fmaxf(t4.x, t4.y), fmaxf(t4.z, t4.w));
        m = wred_max(m);
        if (tid == 0) pmax[part] = m;
    }
    int j = jg * 256 + tid;
    float tj = s2[j];
    float negc = -(s1[j] + gab[0]);
    int jloc = j - part * 256;
    int cntR = 0, cntK = 0;
    #pragma unroll 4
    for (int q = 0; q < 64; ++q) {
        float4 t4 = ts4[q];
        int rb = q * 4;
        cntR += (t4.x < tj || (t4.x == tj && rb     < jloc)) ? 1 : 0;
        cntR += (t4.y < tj || (t4.y == tj && rb + 1 < jloc)) ? 1 : 0;
        cntR += (t4.z < tj || (t4.z == tj && rb + 2 < jloc)) ? 1 : 0;
        cntR += (t4.w < tj || (t4.w == tj && rb + 3 < jloc)) ? 1 : 0;
        cntK += (t4.x <= negc) ? 1 : 0;
        cntK += (t4.y <= negc) ? 1 : 0;
        cntK += (t4.z <= negc) ? 1 : 0;
        cntK += (t4.w <= negc) ? 1 : 0;
    }
    rankPart[part * 8192 + j] = cntR;
    kPart[part * 8192 + j]    = cntK;
}

// C: sum partials -> jsorted (index scatter), e^t / e^{0.2t} in sorted order, kk
__global__ __launch_bounds__(256) void kC_scatter(
        const float* __restrict__ s2,
        const int* __restrict__ rankPart, const int* __restrict__ kPart,
        int* __restrict__ jsorted, float* __restrict__ e1so, float* __restrict__ e2so,
        int* __restrict__ kk) {
    int j = blockIdx.x * 256 + threadIdx.x;
    int r = 0, kq = 0;
    #pragma unroll
    for (int p = 0; p < 32; ++p) { r += rankPart[p * 8192 + j]; kq += kPart[p * 8192 + j]; }
    float t = s2[j];
    jsorted[r] = j;
    e1so[r] = expf(t);
    e2so[r] = expf(0.2f * t);
    kk[j] = kq;
}

// D: dual-role, 128 blocks. bid<64: chunk sums. bid>=64: chunk-local prefixes (no base).
__global__ __launch_bounds__(256) void kD_dual(
        const float* __restrict__ Wh, const int* __restrict__ jsorted,
        const float* __restrict__ e1so, const float* __restrict__ e2so,
        float* __restrict__ csP, float* __restrict__ csN,
        float* __restrict__ csp, float* __restrict__ csn,
        float* __restrict__ PLpos, float* __restrict__ PLneg,
        float* __restrict__ pLp, float* __restrict__ pLn) {
    __shared__ float ldsA[4][64], ldsB[4][64];
    int bid = blockIdx.x, tid = threadIdx.x;
    int h = tid & 63, w = tid >> 6;
    if (bid < 64) {
        int ch = bid;
        int rb = ch * 128 + w * 32;
        double aP = 0.0, aN = 0.0;
        #pragma unroll
        for (int r = 0; r < 32; ++r) {
            int j = jsorted[rb + r];
            float wv = Wh[j * 64 + h];
            aP += e1so[rb + r] * wv;
            aN += e2so[rb + r] * wv;
        }
        ldsA[w][h] = (float)aP; ldsB[w][h] = (float)aN;
        __syncthreads();
        if (w == 0) {
            csP[ch * 64 + h] = ldsA[0][h] + ldsA[1][h] + ldsA[2][h] + ldsA[3][h];
        } else if (w == 1) {
            csN[ch * 64 + h] = ldsB[0][h] + ldsB[1][h] + ldsB[2][h] + ldsB[3][h];
        } else if (w == 2) {
            float vv = e1so[ch * 128 + h] + e1so[ch * 128 + 64 + h];
            vv = wred_sum(vv);
            if (h == 0) csp[ch] = vv;
        } else {
            float vv = e2so[ch * 128 + h] + e2so[ch * 128 + 64 + h];
            vv = wred_sum(vv);
            if (h == 0) csn[ch] = vv;
        }
    } else {
        int ch = bid - 64;
        int rb = ch * 128 + w * 32;
        float v[32], u[32];
        #pragma unroll
        for (int r = 0; r < 32; ++r) {
            int j = jsorted[rb + r];
            float wv = Wh[j * 64 + h];
            v[r] = e1so[rb + r] * wv;
            u[r] = e2so[rb + r] * wv;
        }
        double sP = 0.0, sN = 0.0;
        #pragma unroll
        for (int r = 0; r < 32; ++r) { sP += v[r]; sN += u[r]; }
        ldsA[w][h] = (float)sP; ldsB[w][h] = (float)sN;
        __syncthreads();
        float offP = 0.f, offN = 0.f;
        #pragma unroll
        for (int w2 = 0; w2 < 4; ++w2) if (w2 < w) { offP += ldsA[w2][h]; offN += ldsB[w2][h]; }
        double a = 0.0;
        #pragma unroll
        for (int r = 0; r < 32; ++r) { PLpos[(rb + r) * 64 + h] = offP + (float)a; a += v[r]; }
        a = 0.0;
        #pragma unroll
        for (int r = 0; r < 32; ++r) { PLneg[(rb + r) * 64 + h] = offN + (float)a; a += u[r]; }
        if (w == 0) {
            int lane = h;
            float v0 = e1so[ch * 128 + lane], v1 = e1so[ch * 128 + 64 + lane];
            float i0 = wscan_incl(v0, lane);
            float t0 = __shfl(i0, 63);
            float i1 = wscan_incl(v1, lane);
            pLp[ch * 128 + lane]      = i0 - v0;
            pLp[ch * 128 + 64 + lane] = t0 + i1 - v1;
        } else if (w == 1) {
            int lane = h;
            float v0 = e2so[ch * 128 + lane], v1 = e2so[ch * 128 + 64 + lane];
            float i0 = wscan_incl(v0, lane);
            float t0 = __shfl(i0, 63);
            float i1 = wscan_incl(v1, lane);
            pLn[ch * 128 + lane]      = i0 - v0;
            pLn[ch * 128 + 64 + lane] = t0 + i1 - v1;
        }
    }
}

// F: per-node hp (chunk-base built in LDS, coalesced serial scans) + time-attn -> h2
__global__ __launch_bounds__(256) void kF_node(
        const float* __restrict__ s1, const int* __restrict__ kk,
        const float* __restrict__ pmax, const float* __restrict__ gab,
        const float* __restrict__ PLpos, const float* __restrict__ PLneg,
        const float* __restrict__ pLp, const float* __restrict__ pLn,
        const float* __restrict__ csP, const float* __restrict__ csN,
        const float* __restrict__ csp, const float* __restrict__ csn,
        const float* __restrict__ taW, const float* __restrict__ tab,
        float* __restrict__ h2) {
    __shared__ float4 wt4[1024];     // taW: [kk4*64 + h]
    __shared__ float hl[16 * 64];
    __shared__ float cpP[65 * 64], cpN[65 * 64];   // exclusive chunk-base prefixes
    __shared__ float cpp[65], cpn[65];
    int tid = threadIdx.x;
    int h = tid & 63, w = tid >> 6;
    for (int fidx = tid; fidx < 1024; fidx += 256) {
        int h_ = fidx >> 4, kk4 = fidx & 15;
        wt4[kk4 * 64 + h_] = ((const float4*)taW)[fidx];
    }
    if (w == 0) {
        double a = 0.0;
        for (int ch = 0; ch < 64; ++ch) { cpP[ch * 64 + h] = (float)a; a += csP[ch * 64 + h]; }
        cpP[64 * 64 + h] = (float)a;
    } else if (w == 1) {
        double a = 0.0;
        for (int ch = 0; ch < 64; ++ch) { cpN[ch * 64 + h] = (float)a; a += csN[ch * 64 + h]; }
        cpN[64 * 64 + h] = (float)a;
    } else if (w == 2) {
        float v = csp[h];
        float i = wscan_incl(v, h);
        cpp[h] = i - v;
        if (h == 63) cpp[64] = i;
    } else {
        float v = csn[h];
        float i = wscan_incl(v, h);
        cpn[h] = i - v;
        if (h == 63) cpn[64] = i;
    }
    float tmx = pmax[tid & 31];
    tmx = wred_max(tmx);
    __syncthreads();
    float gabv = gab[0];
    float tabv = tab[h];
    float Tp  = cpP[64 * 64 + h];
    float ppT = cpp[64];
    for (int r = 0; r < 4; ++r) {
        int n = blockIdx.x * 16 + w * 4 + r;
        float c = s1[n] + gabv;
        int k = kk[n];
        int ch = k >> 7;
        float PLpv = 0.f, PLnv = 0.f, pLpv = 0.f, pLnv = 0.f;
        if (k < Nn) {
            PLpv = PLpos[k * 64 + h]; PLnv = PLneg[k * 64 + h];
            pLpv = pLp[k];            pLnv = pLn[k];
        }
        float Pp = cpP[ch * 64 + h] + PLpv;
        float Pn = cpN[ch * 64 + h] + PLnv;
        float qp = cpp[ch] + pLpv;
        float qn = cpn[ch] + pLnv;
        float z = c + tmx;
        float m = (z >= 0.f) ? z : 0.2f * z;
        float E1 = expf(c - m), E2 = expf(0.2f * c - m);
        float num = E1 * (Tp - Pp) + E2 * Pn;
        float den = E1 * (ppT - qp) + E2 * qn;
        float hp = num / den;
        int slot = w * 4 + r;
        hl[slot * 64 + h] = hp;
        float vv = tabv;
        const float4* hlr = (const float4*)&hl[slot * 64];
        #pragma unroll
        for (int kk4 = 0; kk4 < 16; ++kk4) {
            float4 w4 = wt4[kk4 * 64 + h];
            float4 x4 = hlr[kk4];
            vv += w4.x * x4.x + w4.y * x4.y + w4.z * x4.z + w4.w * x4.w;
        }
        float mx = wred_max(vv);
        float e = expf(vv - mx);
        float se = wred_sum(e);
        h2[n * 64 + h] = hp * (e / se);
    }
}

// G: mean over S + MLP head -> out
__global__ __launch_bounds__(256) void kG_pool(
        const float* __restrict__ h2,
        const float* __restrict__ p1W, const float* __restrict__ p1b,
        const float* __restrict__ p2W, const float* __restrict__ p2b,
        float* __restrict__ out) {
    __shared__ float pacc[4 * 64];
    __shared__ float pl[64];
    __shared__ float p1s[32 * 65];
    int tid = threadIdx.x, b = blockIdx.x;
    int w = tid >> 6, h = tid & 63;
    for (int idx = tid; idx < 2048; idx += 256) {
        int q = idx >> 6, kq = idx & 63;
        p1s[q * 65 + kq] = p1W[idx];
    }
    float a = 0.f;
    for (int s = w * 32; s < w * 32 + 32; ++s) a += h2[(b * Sd + s) * 64 + h];
    pacc[w * 64 + h] = a;
    __syncthreads();
    if (w == 0) {
        float pooled = (pacc[h] + pacc[64 + h] + pacc[128 + h] + pacc[192 + h]) * (1.f / 128.f);
        pl[h] = pooled;
        float val = 0.f;
        if (h < 32) {
            float acc = p1b[h];
            #pragma unroll
            for (int kq = 0; kq < 64; ++kq) acc += p1s[h * 65 + kq] * pl[kq];
            val = p2W[h] * fmaxf(acc, 0.f);
        }
        val = wred_sum(val);
        if (h == 0) out[b] = val + p2b[0];
    }
}

extern "C" void kernel_launch(void* const* d_in, const int* in_sizes, int n_in,
                              void* d_out, int out_size, void* d_ws, size_t ws_size,
                              hipStream_t stream) {
    const float* x    = (const float*)d_in[0];
    const float* c1w  = (const float*)d_in[1];
    const float* c1b  = (const float*)d_in[2];
    const float* b1g  = (const float*)d_in[3];
    const float* b1b  = (const float*)d_in[4];
    const float* b1m  = (const float*)d_in[5];
    const float* b1v  = (const float*)d_in[6];
    const float* c2w  = (const float*)d_in[7];
    const float* c2b  = (const float*)d_in[8];
    const float* b2g  = (const float*)d_in[9];
    const float* b2b  = (const float*)d_in[10];
    const float* b2m  = (const float*)d_in[11];
    const float* b2v  = (const float*)d_in[12];
    const float* gW   = (const float*)d_in[13];
    const float* gWb  = (const float*)d_in[14];
    const float* ga1  = (const float*)d_in[15];
    const float* ga2  = (const float*)d_in[16];
    const float* gab  = (const float*)d_in[17];
    const float* taW  = (const float*)d_in[18];
    const float* tab  = (const float*)d_in[19];
    const float* p1W  = (const float*)d_in[20];
    const float* p1b  = (const float*)d_in[21];
    const float* p2W  = (const float*)d_in[22];
    const float* p2b  = (const float*)d_in[23];
    float* out = (float*)d_out;

    float* ws = (float*)d_ws;
    float* Wh      = ws;                    // 524288
    float* s1      = Wh + 524288;           // 8192
    float* s2v     = s1 + 8192;             // 8192
    float* e1so    = s2v + 8192;            // 8192
    float* e2so    = e1so + 8192;           // 8192
    float* csP     = e2so + 8192;           // 4096
    float* csN     = csP + 4096;            // 4096
    float* csp     = csN + 4096;            // 64
    float* csn     = csp + 64;              // 64
    float* pmax    = csn + 64;              // 64 (32 used)
    float* pLp     = pmax + 64;             // 8192
    float* pLn     = pLp + 8192;            // 8192
    float* PLpos   = pLn + 8192;            // 524288
    float* PLneg   = PLpos + 524288;        // 524288
    int*   jsorted = (int*)(PLneg + 524288);// 8192
    int*   kk      = jsorted + 8192;        // 8192
    int*   rankPart= kk + 8192;             // 262144
    int*   kPart   = rankPart + 262144;     // 262144
    float* h2      = (float*)rankPart;      // alias: rankPart/kPart dead after kC

    kA_feat_wh<<<256, 256, 0, stream>>>(x, c1w, c1b, b1g, b1b, b1m, b1v,
                                        c2w, c2b, b2g, b2b, b2m, b2v,
                                        gW, gWb, ga1, ga2, Wh, s1, s2v);
    kB_rank<<<1024, 256, 0, stream>>>(s2v, s1, gab, rankPart, kPart, pmax);
    kC_scatter<<<32, 256, 0, stream>>>(s2v, rankPart, kPart, jsorted, e1so, e2so, kk);
    kD_dual<<<128, 256, 0, stream>>>(Wh, jsorted, e1so, e2so, csP, csN, csp, csn,
                                     PLpos, PLneg, pLp, pLn);
    kF_node<<<512, 256, 0, stream>>>(s1, kk, pmax, gab, PLpos, PLneg, pLp, pLn,
                                     csP, csN, csp, csn, taW, tab, h2);
    kG_pool<<<64, 256, 0, stream>>>(h2, p1W, p1b, p2W, p2b, out);
}